// Round 2
// baseline (784.202 us; speedup 1.0000x reference)
//
#include <hip/hip_runtime.h>

#define N_NODES 100000
#define N_EDGES 3200000
#define NFEAT 256
#define HID 32
#define NCLASS 16

#define SCAN_TPB 256
#define SCAN_EPB 1024
#define SCAN_NBLK ((N_NODES + SCAN_EPB - 1) / SCAN_EPB)   // 98

// ---------------- init: deg=1 (self-loop), cnt=0 ----------------
__global__ void k_init(float* __restrict__ deg, int* __restrict__ cnt) {
    int i = blockIdx.x * 256 + threadIdx.x;
    if (i < N_NODES) { deg[i] = 1.0f; cnt[i] = 0; }
}

// ---------------- per-edge: weighted degree + edge count at target ----------------
__global__ void k_edge_deg(const int* __restrict__ col, const float* __restrict__ w,
                           float* __restrict__ deg, int* __restrict__ cnt) {
    int e = blockIdx.x * 256 + threadIdx.x;
    if (e < N_EDGES) {
        int c = col[e];
        atomicAdd(&deg[c], w[e]);
        atomicAdd(&cnt[c], 1);
    }
}

__global__ void k_dinv(float* __restrict__ deg) {
    int i = blockIdx.x * 256 + threadIdx.x;
    if (i < N_NODES) {
        float d = deg[i];
        deg[i] = (d > 0.0f) ? rsqrtf(d) : 0.0f;
    }
}

// ---------------- exclusive scan of cnt -> offs (3 kernels) ----------------
__global__ __launch_bounds__(SCAN_TPB) void k_scanA(const int* __restrict__ cnt,
                                                    int* __restrict__ offs,
                                                    int* __restrict__ bsum) {
    __shared__ int s[SCAN_TPB];
    int t = threadIdx.x;
    int base = blockIdx.x * SCAN_EPB + t * 4;
    int v0 = (base + 0 < N_NODES) ? cnt[base + 0] : 0;
    int v1 = (base + 1 < N_NODES) ? cnt[base + 1] : 0;
    int v2 = (base + 2 < N_NODES) ? cnt[base + 2] : 0;
    int v3 = (base + 3 < N_NODES) ? cnt[base + 3] : 0;
    int sum = v0 + v1 + v2 + v3;
    s[t] = sum;
    __syncthreads();
    for (int off = 1; off < SCAN_TPB; off <<= 1) {
        int x = (t >= off) ? s[t - off] : 0;
        __syncthreads();
        s[t] += x;
        __syncthreads();
    }
    int excl = s[t] - sum;
    if (t == SCAN_TPB - 1) bsum[blockIdx.x] = s[t];
    int run = excl;
    if (base + 0 < N_NODES) offs[base + 0] = run; run += v0;
    if (base + 1 < N_NODES) offs[base + 1] = run; run += v1;
    if (base + 2 < N_NODES) offs[base + 2] = run; run += v2;
    if (base + 3 < N_NODES) offs[base + 3] = run;
}

__global__ __launch_bounds__(128) void k_scanB(int* __restrict__ bsum) {
    __shared__ int s[128];
    int t = threadIdx.x;
    int v = (t < SCAN_NBLK) ? bsum[t] : 0;
    s[t] = v;
    __syncthreads();
    for (int off = 1; off < 128; off <<= 1) {
        int x = (t >= off) ? s[t - off] : 0;
        __syncthreads();
        s[t] += x;
        __syncthreads();
    }
    if (t < SCAN_NBLK) bsum[t] = s[t] - v;   // exclusive
}

__global__ __launch_bounds__(SCAN_TPB) void k_scanC(int* __restrict__ offs,
                                                    const int* __restrict__ bsum,
                                                    int* __restrict__ cursor) {
    int t = threadIdx.x;
    int add = bsum[blockIdx.x];
    int base = blockIdx.x * SCAN_EPB + t * 4;
    #pragma unroll
    for (int i = 0; i < 4; ++i) {
        int idx = base + i;
        if (idx < N_NODES) {
            int o = offs[idx] + add;
            offs[idx] = o;
            cursor[idx] = o;
        }
    }
    if (blockIdx.x == 0 && t == 0) offs[N_NODES] = N_EDGES;
}

// ---------------- fill CSR: ein[pos] = (src, norm) ----------------
__global__ void k_fill(const int* __restrict__ row, const int* __restrict__ col,
                       const float* __restrict__ w, const float* __restrict__ dinv,
                       int* __restrict__ cursor, float2* __restrict__ ein) {
    int e = blockIdx.x * 256 + threadIdx.x;
    if (e >= N_EDGES) return;
    int r = row[e], c = col[e];
    float nrm = dinv[r] * w[e] * dinv[c];
    int pos = atomicAdd(&cursor[c], 1);
    ein[pos] = make_float2(__int_as_float(r), nrm);
}

// ---------------- GEMM1: xw = x @ W1, 128-row tile, TM=8 TN=4 ----------------
__global__ __launch_bounds__(128) void k_gemm1(const float* __restrict__ x,
                                               const float* __restrict__ W1,
                                               float* __restrict__ xw) {
    __shared__ float sW[NFEAT * HID];     // 32KB, [k][c]
    __shared__ float sX[32][132];         // k-major chunk, pad 132 (4-way write conflict only)
    int t = threadIdx.x;
    #pragma unroll
    for (int i = 0; i < 16; ++i) {
        int idx = (t + i * 128) * 4;
        *(float4*)&sW[idx] = *(const float4*)&W1[idx];
    }
    long rowbase = (long)blockIdx.x * 128;
    int tr = t >> 3;          // 0..15 -> rows tr*8..tr*8+7
    int tc = t & 7;           // 0..7  -> cols tc*4..tc*4+3
    float acc[8][4] = {};
    for (int k0 = 0; k0 < NFEAT; k0 += 32) {
        __syncthreads();
        #pragma unroll
        for (int p = 0; p < 8; ++p) {
            int rt = (t >> 3) + p * 16;
            int kk = (t & 7) * 4;
            long grow = rowbase + rt;
            float4 v = make_float4(0.f, 0.f, 0.f, 0.f);
            if (grow < N_NODES) v = *(const float4*)&x[grow * NFEAT + k0 + kk];
            sX[kk + 0][rt] = v.x; sX[kk + 1][rt] = v.y;
            sX[kk + 2][rt] = v.z; sX[kk + 3][rt] = v.w;
        }
        __syncthreads();
        #pragma unroll 8
        for (int kk = 0; kk < 32; ++kk) {
            float xv[8], wv[4];
            *(float4*)&xv[0] = *(float4*)&sX[kk][tr * 8];
            *(float4*)&xv[4] = *(float4*)&sX[kk][tr * 8 + 4];
            *(float4*)&wv[0] = *(float4*)&sW[(k0 + kk) * HID + tc * 4];
            #pragma unroll
            for (int m = 0; m < 8; ++m)
                #pragma unroll
                for (int n = 0; n < 4; ++n)
                    acc[m][n] = fmaf(xv[m], wv[n], acc[m][n]);
        }
    }
    #pragma unroll
    for (int m = 0; m < 8; ++m) {
        long r = rowbase + tr * 8 + m;
        if (r < N_NODES) {
            float4 o = make_float4(acc[m][0], acc[m][1], acc[m][2], acc[m][3]);
            *(float4*)&xw[r * HID + tc * 4] = o;
        }
    }
}

// ---------------- gather layer 1: agg + bias + ReLU ----------------
__global__ __launch_bounds__(256) void k_gather1(const float* __restrict__ xw,
                                                 const float* __restrict__ dinv,
                                                 const float2* __restrict__ ein,
                                                 const int* __restrict__ offs,
                                                 const float* __restrict__ b1,
                                                 float* __restrict__ h) {
    int idx = blockIdx.x * 256 + threadIdx.x;   // N*32 exact
    int n = idx >> 5, c = idx & 31;
    float di = dinv[n];
    float acc = xw[(long)n * HID + c] * di * di;   // self-loop
    int s = offs[n], e = offs[n + 1];
    for (int p = s; p < e; ++p) {
        float2 pr = ein[p];
        int r = __float_as_int(pr.x);
        acc = fmaf(xw[(long)r * HID + c], pr.y, acc);
    }
    float v = acc + b1[c];
    h[idx] = v > 0.f ? v : 0.f;
}

// ---------------- GEMM2: hw = h @ W2, 64-row tile, 4 cols/thread ----------------
__global__ __launch_bounds__(256) void k_gemm2(const float* __restrict__ h,
                                               const float* __restrict__ W2,
                                               float* __restrict__ hw) {
    __shared__ float sH[64][33];
    __shared__ float sW2[HID * NCLASS];   // 512
    int t = threadIdx.x;
    if (t < 128) {
        int idx = t * 4;
        *(float4*)&sW2[idx] = *(const float4*)&W2[idx];
    }
    long base = (long)blockIdx.x * 64;
    #pragma unroll
    for (int i = 0; i < 2; ++i) {
        int idx = t + i * 256;            // 0..511
        int rt = idx >> 3, kk = (idx & 7) * 4;
        long gr = base + rt;
        float4 v = make_float4(0.f, 0.f, 0.f, 0.f);
        if (gr < N_NODES) v = *(const float4*)&h[gr * HID + kk];
        sH[rt][kk + 0] = v.x; sH[rt][kk + 1] = v.y;
        sH[rt][kk + 2] = v.z; sH[rt][kk + 3] = v.w;
    }
    __syncthreads();
    int r = t >> 2, c4 = (t & 3) * 4;
    float acc[4] = {};
    #pragma unroll
    for (int k = 0; k < HID; ++k) {
        float hv = sH[r][k];
        float wv[4];
        *(float4*)&wv[0] = *(float4*)&sW2[k * NCLASS + c4];
        #pragma unroll
        for (int n = 0; n < 4; ++n) acc[n] = fmaf(hv, wv[n], acc[n]);
    }
    long gr = base + r;
    if (gr < N_NODES) {
        float4 o = make_float4(acc[0], acc[1], acc[2], acc[3]);
        *(float4*)&hw[gr * NCLASS + c4] = o;
    }
}

// ---------------- gather layer 2: agg + bias + log_softmax ----------------
__global__ __launch_bounds__(256) void k_gather2(const float* __restrict__ hw,
                                                 const float* __restrict__ dinv,
                                                 const float2* __restrict__ ein,
                                                 const int* __restrict__ offs,
                                                 const float* __restrict__ b2,
                                                 float* __restrict__ out) {
    int idx = blockIdx.x * 256 + threadIdx.x;   // N*16 exact
    int n = idx >> 4, c = idx & 15;
    float di = dinv[n];
    float acc = hw[(long)n * NCLASS + c] * di * di;
    int s = offs[n], e = offs[n + 1];
    for (int p = s; p < e; ++p) {
        float2 pr = ein[p];
        int r = __float_as_int(pr.x);
        acc = fmaf(hw[(long)r * NCLASS + c], pr.y, acc);
    }
    float v = acc + b2[c];
    float m = v;
    #pragma unroll
    for (int d = 1; d < 16; d <<= 1) m = fmaxf(m, __shfl_xor(m, d, 16));
    float sum = __expf(v - m);
    #pragma unroll
    for (int d = 1; d < 16; d <<= 1) sum += __shfl_xor(sum, d, 16);
    out[idx] = v - m - __logf(sum);
}

extern "C" void kernel_launch(void* const* d_in, const int* in_sizes, int n_in,
                              void* d_out, int out_size, void* d_ws, size_t ws_size,
                              hipStream_t stream) {
    const float* x  = (const float*)d_in[0];
    const int*   ei = (const int*)d_in[1];
    const float* w  = (const float*)d_in[2];
    const float* W1 = (const float*)d_in[3];
    const float* b1 = (const float*)d_in[4];
    const float* W2 = (const float*)d_in[5];
    const float* b2 = (const float*)d_in[6];
    float* out = (float*)d_out;

    const int* row = ei;
    const int* col = ei + N_EDGES;

    float* ws = (float*)d_ws;
    float2* ein = (float2*)ws;                              // 2E floats (25.6MB)
    float*  xw  = ws + 2 * (size_t)N_EDGES;                 // N*32
    float*  h   = xw + (size_t)N_NODES * HID;               // N*32
    float*  hw  = xw;                                       // alias: xw dead after gather1
    float*  deg = h + (size_t)N_NODES * HID;                // N (becomes dinv)
    int* cnt    = (int*)(deg + N_NODES);                    // N
    int* offs   = cnt + N_NODES;                            // N+1
    int* cursor = offs + N_NODES + 1;                       // N
    int* bsum   = cursor + N_NODES;                         // 128

    const int B = 256;

    k_init<<<(N_NODES + B - 1) / B, B, 0, stream>>>(deg, cnt);
    k_edge_deg<<<(N_EDGES + B - 1) / B, B, 0, stream>>>(col, w, deg, cnt);
    k_dinv<<<(N_NODES + B - 1) / B, B, 0, stream>>>(deg);

    k_scanA<<<SCAN_NBLK, SCAN_TPB, 0, stream>>>(cnt, offs, bsum);
    k_scanB<<<1, 128, 0, stream>>>(bsum);
    k_scanC<<<SCAN_NBLK, SCAN_TPB, 0, stream>>>(offs, bsum, cursor);

    k_fill<<<(N_EDGES + B - 1) / B, B, 0, stream>>>(row, col, w, deg, cursor, ein);

    k_gemm1<<<(N_NODES + 127) / 128, 128, 0, stream>>>(x, W1, xw);
    k_gather1<<<(N_NODES * HID) / B, B, 0, stream>>>(xw, deg, ein, offs, b1, h);

    k_gemm2<<<(N_NODES + 63) / 64, B, 0, stream>>>(h, W2, hw);
    k_gather2<<<(N_NODES * NCLASS) / B, B, 0, stream>>>(hw, deg, ein, offs, b2, out);
}

// Round 3
// 547.787 us; speedup vs baseline: 1.4316x; 1.4316x over previous
//
#include <hip/hip_runtime.h>

#define N_NODES 100000
#define N_EDGES 3200000
#define NFEAT 256
#define HID 32
#define NCLASS 16

#define SCAN_TPB 256
#define SCAN_EPB 1024
#define SCAN_NBLK ((N_NODES + SCAN_EPB - 1) / SCAN_EPB)   // 98

#define FX_SCALE 268435456.0f    // 2^28
#define FX_INV   3.7252902984619140625e-9f
#define FX_MASK  0xFFFFFFFFFFFFULL

// ---------------- zero packed (count<<48 | fx48 weighted degree) ----------------
__global__ void k_zero(unsigned long long* __restrict__ packed) {
    int i = blockIdx.x * 256 + threadIdx.x;
    if (i < N_NODES) packed[i] = 0ULL;
}

// ---------------- one 64-bit atomic per edge: count + weighted deg + position ----------------
__global__ void k_cnt(const int* __restrict__ col, const float* __restrict__ w,
                      unsigned long long* __restrict__ packed,
                      unsigned short* __restrict__ pos) {
    int e = blockIdx.x * 256 + threadIdx.x;
    if (e >= N_EDGES) return;
    int c = col[e];
    unsigned long long inc = (1ULL << 48) |
        (unsigned long long)(w[e] * FX_SCALE + 0.5f);
    unsigned long long old = atomicAdd(&packed[c], inc);
    pos[e] = (unsigned short)(old >> 48);
}

// ---------------- dinv from packed ----------------
__global__ void k_dinv(const unsigned long long* __restrict__ packed,
                       float* __restrict__ dinv) {
    int i = blockIdx.x * 256 + threadIdx.x;
    if (i < N_NODES) {
        float d = 1.0f + __ull2float_rn(packed[i] & FX_MASK) * FX_INV;
        dinv[i] = rsqrtf(d);   // d >= 1 always
    }
}

// ---------------- exclusive scan of counts -> offs (3 kernels) ----------------
__global__ __launch_bounds__(SCAN_TPB) void k_scanA(const unsigned long long* __restrict__ packed,
                                                    int* __restrict__ offs,
                                                    int* __restrict__ bsum) {
    __shared__ int s[SCAN_TPB];
    int t = threadIdx.x;
    int base = blockIdx.x * SCAN_EPB + t * 4;
    int v0 = (base + 0 < N_NODES) ? (int)(packed[base + 0] >> 48) : 0;
    int v1 = (base + 1 < N_NODES) ? (int)(packed[base + 1] >> 48) : 0;
    int v2 = (base + 2 < N_NODES) ? (int)(packed[base + 2] >> 48) : 0;
    int v3 = (base + 3 < N_NODES) ? (int)(packed[base + 3] >> 48) : 0;
    int sum = v0 + v1 + v2 + v3;
    s[t] = sum;
    __syncthreads();
    for (int off = 1; off < SCAN_TPB; off <<= 1) {
        int x = (t >= off) ? s[t - off] : 0;
        __syncthreads();
        s[t] += x;
        __syncthreads();
    }
    int excl = s[t] - sum;
    if (t == SCAN_TPB - 1) bsum[blockIdx.x] = s[t];
    int run = excl;
    if (base + 0 < N_NODES) offs[base + 0] = run; run += v0;
    if (base + 1 < N_NODES) offs[base + 1] = run; run += v1;
    if (base + 2 < N_NODES) offs[base + 2] = run; run += v2;
    if (base + 3 < N_NODES) offs[base + 3] = run;
}

__global__ __launch_bounds__(128) void k_scanB(int* __restrict__ bsum) {
    __shared__ int s[128];
    int t = threadIdx.x;
    int v = (t < SCAN_NBLK) ? bsum[t] : 0;
    s[t] = v;
    __syncthreads();
    for (int off = 1; off < 128; off <<= 1) {
        int x = (t >= off) ? s[t - off] : 0;
        __syncthreads();
        s[t] += x;
        __syncthreads();
    }
    if (t < SCAN_NBLK) bsum[t] = s[t] - v;   // exclusive
}

__global__ __launch_bounds__(SCAN_TPB) void k_scanC(int* __restrict__ offs,
                                                    const int* __restrict__ bsum) {
    int t = threadIdx.x;
    int add = bsum[blockIdx.x];
    int base = blockIdx.x * SCAN_EPB + t * 4;
    #pragma unroll
    for (int i = 0; i < 4; ++i) {
        int idx = base + i;
        if (idx < N_NODES) offs[idx] += add;
    }
    if (blockIdx.x == 0 && t == 0) offs[N_NODES] = N_EDGES;
}

// ---------------- fill CSR (no atomics): ein[offs[c]+pos[e]] = (src, norm) ----------------
__global__ void k_fill(const int* __restrict__ row, const int* __restrict__ col,
                       const float* __restrict__ w, const float* __restrict__ dinv,
                       const int* __restrict__ offs, const unsigned short* __restrict__ pos,
                       float2* __restrict__ ein) {
    int e = blockIdx.x * 256 + threadIdx.x;
    if (e >= N_EDGES) return;
    int r = row[e], c = col[e];
    float nrm = dinv[r] * w[e] * dinv[c];
    int p = offs[c] + (int)pos[e];
    ein[p] = make_float2(__int_as_float(r), nrm);
}

// ---------------- GEMM1: xw = x @ W1, 128-row tile, TM=8 TN=4 ----------------
__global__ __launch_bounds__(128) void k_gemm1(const float* __restrict__ x,
                                               const float* __restrict__ W1,
                                               float* __restrict__ xw) {
    __shared__ float sW[NFEAT * HID];     // 32KB, [k][c]
    __shared__ float sX[32][132];
    int t = threadIdx.x;
    #pragma unroll
    for (int i = 0; i < 16; ++i) {
        int idx = (t + i * 128) * 4;
        *(float4*)&sW[idx] = *(const float4*)&W1[idx];
    }
    long rowbase = (long)blockIdx.x * 128;
    int tr = t >> 3;
    int tc = t & 7;
    float acc[8][4] = {};
    for (int k0 = 0; k0 < NFEAT; k0 += 32) {
        __syncthreads();
        #pragma unroll
        for (int p = 0; p < 8; ++p) {
            int rt = (t >> 3) + p * 16;
            int kk = (t & 7) * 4;
            long grow = rowbase + rt;
            float4 v = make_float4(0.f, 0.f, 0.f, 0.f);
            if (grow < N_NODES) v = *(const float4*)&x[grow * NFEAT + k0 + kk];
            sX[kk + 0][rt] = v.x; sX[kk + 1][rt] = v.y;
            sX[kk + 2][rt] = v.z; sX[kk + 3][rt] = v.w;
        }
        __syncthreads();
        #pragma unroll 8
        for (int kk = 0; kk < 32; ++kk) {
            float xv[8], wv[4];
            *(float4*)&xv[0] = *(float4*)&sX[kk][tr * 8];
            *(float4*)&xv[4] = *(float4*)&sX[kk][tr * 8 + 4];
            *(float4*)&wv[0] = *(float4*)&sW[(k0 + kk) * HID + tc * 4];
            #pragma unroll
            for (int m = 0; m < 8; ++m)
                #pragma unroll
                for (int n = 0; n < 4; ++n)
                    acc[m][n] = fmaf(xv[m], wv[n], acc[m][n]);
        }
    }
    #pragma unroll
    for (int m = 0; m < 8; ++m) {
        long r = rowbase + tr * 8 + m;
        if (r < N_NODES) {
            float4 o = make_float4(acc[m][0], acc[m][1], acc[m][2], acc[m][3]);
            *(float4*)&xw[r * HID + tc * 4] = o;
        }
    }
}

// ---------------- gather layer 1: agg + bias + ReLU ----------------
__global__ __launch_bounds__(256) void k_gather1(const float* __restrict__ xw,
                                                 const float* __restrict__ dinv,
                                                 const float2* __restrict__ ein,
                                                 const int* __restrict__ offs,
                                                 const float* __restrict__ b1,
                                                 float* __restrict__ h) {
    int idx = blockIdx.x * 256 + threadIdx.x;   // N*32 exact
    int n = idx >> 5, c = idx & 31;
    float di = dinv[n];
    float acc = xw[(long)n * HID + c] * di * di;   // self-loop
    int s = offs[n], e = offs[n + 1];
    for (int p = s; p < e; ++p) {
        float2 pr = ein[p];
        int r = __float_as_int(pr.x);
        acc = fmaf(xw[(long)r * HID + c], pr.y, acc);
    }
    float v = acc + b1[c];
    h[idx] = v > 0.f ? v : 0.f;
}

// ---------------- GEMM2: hw = h @ W2, 64-row tile ----------------
__global__ __launch_bounds__(256) void k_gemm2(const float* __restrict__ h,
                                               const float* __restrict__ W2,
                                               float* __restrict__ hw) {
    __shared__ float sH[64][33];
    __shared__ float sW2[HID * NCLASS];
    int t = threadIdx.x;
    if (t < 128) {
        int idx = t * 4;
        *(float4*)&sW2[idx] = *(const float4*)&W2[idx];
    }
    long base = (long)blockIdx.x * 64;
    #pragma unroll
    for (int i = 0; i < 2; ++i) {
        int idx = t + i * 256;
        int rt = idx >> 3, kk = (idx & 7) * 4;
        long gr = base + rt;
        float4 v = make_float4(0.f, 0.f, 0.f, 0.f);
        if (gr < N_NODES) v = *(const float4*)&h[gr * HID + kk];
        sH[rt][kk + 0] = v.x; sH[rt][kk + 1] = v.y;
        sH[rt][kk + 2] = v.z; sH[rt][kk + 3] = v.w;
    }
    __syncthreads();
    int r = t >> 2, c4 = (t & 3) * 4;
    float acc[4] = {};
    #pragma unroll
    for (int k = 0; k < HID; ++k) {
        float hv = sH[r][k];
        float wv[4];
        *(float4*)&wv[0] = *(float4*)&sW2[k * NCLASS + c4];
        #pragma unroll
        for (int n = 0; n < 4; ++n) acc[n] = fmaf(hv, wv[n], acc[n]);
    }
    long gr = base + r;
    if (gr < N_NODES) {
        float4 o = make_float4(acc[0], acc[1], acc[2], acc[3]);
        *(float4*)&hw[gr * NCLASS + c4] = o;
    }
}

// ---------------- gather layer 2: agg + bias + log_softmax ----------------
__global__ __launch_bounds__(256) void k_gather2(const float* __restrict__ hw,
                                                 const float* __restrict__ dinv,
                                                 const float2* __restrict__ ein,
                                                 const int* __restrict__ offs,
                                                 const float* __restrict__ b2,
                                                 float* __restrict__ out) {
    int idx = blockIdx.x * 256 + threadIdx.x;   // N*16 exact
    int n = idx >> 4, c = idx & 15;
    float di = dinv[n];
    float acc = hw[(long)n * NCLASS + c] * di * di;
    int s = offs[n], e = offs[n + 1];
    for (int p = s; p < e; ++p) {
        float2 pr = ein[p];
        int r = __float_as_int(pr.x);
        acc = fmaf(hw[(long)r * NCLASS + c], pr.y, acc);
    }
    float v = acc + b2[c];
    float m = v;
    #pragma unroll
    for (int d = 1; d < 16; d <<= 1) m = fmaxf(m, __shfl_xor(m, d, 16));
    float sum = __expf(v - m);
    #pragma unroll
    for (int d = 1; d < 16; d <<= 1) sum += __shfl_xor(sum, d, 16);
    out[idx] = v - m - __logf(sum);
}

extern "C" void kernel_launch(void* const* d_in, const int* in_sizes, int n_in,
                              void* d_out, int out_size, void* d_ws, size_t ws_size,
                              hipStream_t stream) {
    const float* x  = (const float*)d_in[0];
    const int*   ei = (const int*)d_in[1];
    const float* w  = (const float*)d_in[2];
    const float* W1 = (const float*)d_in[3];
    const float* b1 = (const float*)d_in[4];
    const float* W2 = (const float*)d_in[5];
    const float* b2 = (const float*)d_in[6];
    float* out = (float*)d_out;

    const int* row = ei;
    const int* col = ei + N_EDGES;

    float* ws = (float*)d_ws;
    float2* ein = (float2*)ws;                                    // 2E floats (25.6MB)
    float*  xw  = ws + 2 * (size_t)N_EDGES;                       // N*32
    float*  h   = xw + (size_t)N_NODES * HID;                     // N*32
    float*  hw  = xw;                                             // alias: xw dead after gather1
    unsigned long long* packed = (unsigned long long*)(h + (size_t)N_NODES * HID);  // N u64 (8B-aligned: offset even)
    float* dinv = (float*)(packed + N_NODES);                     // N
    int* offs   = (int*)(dinv + N_NODES);                         // N+1
    int* bsum   = offs + N_NODES + 1;                             // 128
    unsigned short* pos = (unsigned short*)(bsum + 128);          // E ushort (6.4MB)

    const int B = 256;

    k_zero<<<(N_NODES + B - 1) / B, B, 0, stream>>>(packed);
    k_cnt<<<(N_EDGES + B - 1) / B, B, 0, stream>>>(col, w, packed, pos);
    k_dinv<<<(N_NODES + B - 1) / B, B, 0, stream>>>(packed, dinv);

    k_scanA<<<SCAN_NBLK, SCAN_TPB, 0, stream>>>(packed, offs, bsum);
    k_scanB<<<1, 128, 0, stream>>>(bsum);
    k_scanC<<<SCAN_NBLK, SCAN_TPB, 0, stream>>>(offs, bsum);

    k_fill<<<(N_EDGES + B - 1) / B, B, 0, stream>>>(row, col, w, dinv, offs, pos, ein);

    k_gemm1<<<(N_NODES + 127) / 128, 128, 0, stream>>>(x, W1, xw);
    k_gather1<<<(N_NODES * HID) / B, B, 0, stream>>>(xw, dinv, ein, offs, b1, h);

    k_gemm2<<<(N_NODES + 63) / 64, B, 0, stream>>>(h, W2, hw);
    k_gather2<<<(N_NODES * NCLASS) / B, B, 0, stream>>>(hw, dinv, ein, offs, b2, out);
}

// Round 4
// 396.089 us; speedup vs baseline: 1.9799x; 1.3830x over previous
//
#include <hip/hip_runtime.h>

#define N_NODES 100000
#define N_EDGES 3200000
#define NFEAT 256
#define HID 32
#define NCLASS 16
#define NSH 8

#define SCAN_TPB 256
#define SCAN_EPB 1024
#define SCAN_NBLK ((N_NODES + SCAN_EPB - 1) / SCAN_EPB)   // 98

#define FX_SCALE 268435456.0f    // 2^28
#define FX_INV   3.7252902984619140625e-9f
#define FX_MASK  0xFFFFFFFFFFFFULL

typedef unsigned long long u64;

// ---------------- zero sharded packed counters ----------------
__global__ void k_zero(u64* __restrict__ packed_sh) {
    int i = blockIdx.x * 256 + threadIdx.x;
    if (i < NSH * N_NODES) packed_sh[i] = 0ULL;
}

// ---- one u64 atomic per edge into XCD-local shard: count + weighted deg + position ----
__global__ void k_cnt(const int* __restrict__ col, const float* __restrict__ w,
                      u64* __restrict__ packed_sh, unsigned short* __restrict__ pos) {
    int e = blockIdx.x * 256 + threadIdx.x;
    if (e >= N_EDGES) return;
    int c = col[e];
    int s = (e >> 8) & (NSH - 1);   // == blockIdx.x & 7 ~ XCD id
    u64 inc = (1ULL << 48) | (u64)(w[e] * FX_SCALE + 0.5f);
    u64 old = atomicAdd(&packed_sh[(size_t)s * N_NODES + c], inc);
    pos[e] = (unsigned short)(old >> 48);
}

// ---- reduce shards: total count, dinv, per-node shard prefix ----
__global__ void k_reduce(const u64* __restrict__ packed_sh, float* __restrict__ dinv,
                         int* __restrict__ cnt_total, int* __restrict__ shard_pref) {
    int i = blockIdx.x * 256 + threadIdx.x;
    if (i >= N_NODES) return;
    int run = 0;
    u64 lowsum = 0;
    #pragma unroll
    for (int s = 0; s < NSH; ++s) {
        u64 v = packed_sh[(size_t)s * N_NODES + i];
        shard_pref[s * N_NODES + i] = run;
        run += (int)(v >> 48);
        lowsum += (v & FX_MASK);
    }
    cnt_total[i] = run;
    float d = 1.0f + __ull2float_rn(lowsum) * FX_INV;
    dinv[i] = rsqrtf(d);   // d >= 1 always
}

// ---------------- exclusive scan of counts -> offs (3 kernels) ----------------
__global__ __launch_bounds__(SCAN_TPB) void k_scanA(const int* __restrict__ cnt,
                                                    int* __restrict__ offs,
                                                    int* __restrict__ bsum) {
    __shared__ int s[SCAN_TPB];
    int t = threadIdx.x;
    int base = blockIdx.x * SCAN_EPB + t * 4;
    int v0 = (base + 0 < N_NODES) ? cnt[base + 0] : 0;
    int v1 = (base + 1 < N_NODES) ? cnt[base + 1] : 0;
    int v2 = (base + 2 < N_NODES) ? cnt[base + 2] : 0;
    int v3 = (base + 3 < N_NODES) ? cnt[base + 3] : 0;
    int sum = v0 + v1 + v2 + v3;
    s[t] = sum;
    __syncthreads();
    for (int off = 1; off < SCAN_TPB; off <<= 1) {
        int x = (t >= off) ? s[t - off] : 0;
        __syncthreads();
        s[t] += x;
        __syncthreads();
    }
    int excl = s[t] - sum;
    if (t == SCAN_TPB - 1) bsum[blockIdx.x] = s[t];
    int run = excl;
    if (base + 0 < N_NODES) offs[base + 0] = run; run += v0;
    if (base + 1 < N_NODES) offs[base + 1] = run; run += v1;
    if (base + 2 < N_NODES) offs[base + 2] = run; run += v2;
    if (base + 3 < N_NODES) offs[base + 3] = run;
}

__global__ __launch_bounds__(128) void k_scanB(int* __restrict__ bsum) {
    __shared__ int s[128];
    int t = threadIdx.x;
    int v = (t < SCAN_NBLK) ? bsum[t] : 0;
    s[t] = v;
    __syncthreads();
    for (int off = 1; off < 128; off <<= 1) {
        int x = (t >= off) ? s[t - off] : 0;
        __syncthreads();
        s[t] += x;
        __syncthreads();
    }
    if (t < SCAN_NBLK) bsum[t] = s[t] - v;   // exclusive
}

__global__ __launch_bounds__(SCAN_TPB) void k_scanC(int* __restrict__ offs,
                                                    const int* __restrict__ bsum) {
    int t = threadIdx.x;
    int add = bsum[blockIdx.x];
    int base = blockIdx.x * SCAN_EPB + t * 4;
    #pragma unroll
    for (int i = 0; i < 4; ++i) {
        int idx = base + i;
        if (idx < N_NODES) offs[idx] += add;
    }
    if (blockIdx.x == 0 && t == 0) offs[N_NODES] = N_EDGES;
}

// ---- fill CSR (no atomics): ein[offs[c]+shard_pref+pos] = (src, norm) ----
__global__ void k_fill(const int* __restrict__ row, const int* __restrict__ col,
                       const float* __restrict__ w, const float* __restrict__ dinv,
                       const int* __restrict__ offs, const int* __restrict__ shard_pref,
                       const unsigned short* __restrict__ pos, float2* __restrict__ ein) {
    int e = blockIdx.x * 256 + threadIdx.x;
    if (e >= N_EDGES) return;
    int r = row[e], c = col[e];
    int s = (e >> 8) & (NSH - 1);
    float nrm = dinv[r] * w[e] * dinv[c];
    int p = offs[c] + shard_pref[s * N_NODES + c] + (int)pos[e];
    ein[p] = make_float2(__int_as_float(r), nrm);
}

// ---------------- GEMM1: xw = x @ W1, 128-row tile, TM=8 TN=4 ----------------
__global__ __launch_bounds__(128) void k_gemm1(const float* __restrict__ x,
                                               const float* __restrict__ W1,
                                               float* __restrict__ xw) {
    __shared__ float sW[NFEAT * HID];     // 32KB, [k][c]
    __shared__ float sX[32][132];
    int t = threadIdx.x;
    #pragma unroll
    for (int i = 0; i < 16; ++i) {
        int idx = (t + i * 128) * 4;
        *(float4*)&sW[idx] = *(const float4*)&W1[idx];
    }
    long rowbase = (long)blockIdx.x * 128;
    int tr = t >> 3;
    int tc = t & 7;
    float acc[8][4] = {};
    for (int k0 = 0; k0 < NFEAT; k0 += 32) {
        __syncthreads();
        #pragma unroll
        for (int p = 0; p < 8; ++p) {
            int rt = (t >> 3) + p * 16;
            int kk = (t & 7) * 4;
            long grow = rowbase + rt;
            float4 v = make_float4(0.f, 0.f, 0.f, 0.f);
            if (grow < N_NODES) v = *(const float4*)&x[grow * NFEAT + k0 + kk];
            sX[kk + 0][rt] = v.x; sX[kk + 1][rt] = v.y;
            sX[kk + 2][rt] = v.z; sX[kk + 3][rt] = v.w;
        }
        __syncthreads();
        #pragma unroll 8
        for (int kk = 0; kk < 32; ++kk) {
            float xv[8], wv[4];
            *(float4*)&xv[0] = *(float4*)&sX[kk][tr * 8];
            *(float4*)&xv[4] = *(float4*)&sX[kk][tr * 8 + 4];
            *(float4*)&wv[0] = *(float4*)&sW[(k0 + kk) * HID + tc * 4];
            #pragma unroll
            for (int m = 0; m < 8; ++m)
                #pragma unroll
                for (int n = 0; n < 4; ++n)
                    acc[m][n] = fmaf(xv[m], wv[n], acc[m][n]);
        }
    }
    #pragma unroll
    for (int m = 0; m < 8; ++m) {
        long r = rowbase + tr * 8 + m;
        if (r < N_NODES) {
            float4 o = make_float4(acc[m][0], acc[m][1], acc[m][2], acc[m][3]);
            *(float4*)&xw[r * HID + tc * 4] = o;
        }
    }
}

// ---- gather layer 1: coalesced edge loads + shfl broadcast, 8-deep gather MLP ----
__global__ __launch_bounds__(256) void k_gather1(const float* __restrict__ xw,
                                                 const float* __restrict__ dinv,
                                                 const float2* __restrict__ ein,
                                                 const int* __restrict__ offs,
                                                 const float* __restrict__ b1,
                                                 float* __restrict__ h) {
    int idx = blockIdx.x * 256 + threadIdx.x;   // N*32 exact
    int n = idx >> 5, c = idx & 31;
    float di = dinv[n];
    const float* xwc = xw + c;
    float acc = xwc[(long)n * HID] * di * di;   // self-loop
    int s = offs[n], e = offs[n + 1];
    for (int p0 = s; p0 < e; p0 += 32) {
        int pl = p0 + c;
        float2 pr = (pl < e) ? ein[pl] : make_float2(__int_as_float(n), 0.f);
        int ri = __float_as_int(pr.x);
        #pragma unroll
        for (int jb = 0; jb < 32; jb += 8) {
            if (p0 + jb >= e) break;
            #pragma unroll
            for (int j = jb; j < jb + 8; ++j) {
                int r = __shfl(ri, j, 32);
                float nm = __shfl(pr.y, j, 32);
                acc = fmaf(xwc[(long)r * HID], nm, acc);
            }
        }
    }
    float v = acc + b1[c];
    h[idx] = v > 0.f ? v : 0.f;
}

// ---------------- GEMM2: hw = h @ W2, 64-row tile ----------------
__global__ __launch_bounds__(256) void k_gemm2(const float* __restrict__ h,
                                               const float* __restrict__ W2,
                                               float* __restrict__ hw) {
    __shared__ float sH[64][33];
    __shared__ float sW2[HID * NCLASS];
    int t = threadIdx.x;
    if (t < 128) {
        int idx = t * 4;
        *(float4*)&sW2[idx] = *(const float4*)&W2[idx];
    }
    long base = (long)blockIdx.x * 64;
    #pragma unroll
    for (int i = 0; i < 2; ++i) {
        int idx = t + i * 256;
        int rt = idx >> 3, kk = (idx & 7) * 4;
        long gr = base + rt;
        float4 v = make_float4(0.f, 0.f, 0.f, 0.f);
        if (gr < N_NODES) v = *(const float4*)&h[gr * HID + kk];
        sH[rt][kk + 0] = v.x; sH[rt][kk + 1] = v.y;
        sH[rt][kk + 2] = v.z; sH[rt][kk + 3] = v.w;
    }
    __syncthreads();
    int r = t >> 2, c4 = (t & 3) * 4;
    float acc[4] = {};
    #pragma unroll
    for (int k = 0; k < HID; ++k) {
        float hv = sH[r][k];
        float wv[4];
        *(float4*)&wv[0] = *(float4*)&sW2[k * NCLASS + c4];
        #pragma unroll
        for (int n = 0; n < 4; ++n) acc[n] = fmaf(hv, wv[n], acc[n]);
    }
    long gr = base + r;
    if (gr < N_NODES) {
        float4 o = make_float4(acc[0], acc[1], acc[2], acc[3]);
        *(float4*)&hw[gr * NCLASS + c4] = o;
    }
}

// ---- gather layer 2: same MLP trick (width 16) + bias + log_softmax ----
__global__ __launch_bounds__(256) void k_gather2(const float* __restrict__ hw,
                                                 const float* __restrict__ dinv,
                                                 const float2* __restrict__ ein,
                                                 const int* __restrict__ offs,
                                                 const float* __restrict__ b2,
                                                 float* __restrict__ out) {
    int idx = blockIdx.x * 256 + threadIdx.x;   // N*16 exact
    int n = idx >> 4, c = idx & 15;
    float di = dinv[n];
    const float* hwc = hw + c;
    float acc = hwc[(long)n * NCLASS] * di * di;
    int s = offs[n], e = offs[n + 1];
    for (int p0 = s; p0 < e; p0 += 16) {
        int pl = p0 + c;
        float2 pr = (pl < e) ? ein[pl] : make_float2(__int_as_float(n), 0.f);
        int ri = __float_as_int(pr.x);
        #pragma unroll
        for (int jb = 0; jb < 16; jb += 8) {
            if (p0 + jb >= e) break;
            #pragma unroll
            for (int j = jb; j < jb + 8; ++j) {
                int r = __shfl(ri, j, 16);
                float nm = __shfl(pr.y, j, 16);
                acc = fmaf(hwc[(long)r * NCLASS], nm, acc);
            }
        }
    }
    float v = acc + b2[c];
    float m = v;
    #pragma unroll
    for (int d = 1; d < 16; d <<= 1) m = fmaxf(m, __shfl_xor(m, d, 16));
    float sum = __expf(v - m);
    #pragma unroll
    for (int d = 1; d < 16; d <<= 1) sum += __shfl_xor(sum, d, 16);
    out[idx] = v - m - __logf(sum);
}

extern "C" void kernel_launch(void* const* d_in, const int* in_sizes, int n_in,
                              void* d_out, int out_size, void* d_ws, size_t ws_size,
                              hipStream_t stream) {
    const float* x  = (const float*)d_in[0];
    const int*   ei = (const int*)d_in[1];
    const float* w  = (const float*)d_in[2];
    const float* W1 = (const float*)d_in[3];
    const float* b1 = (const float*)d_in[4];
    const float* W2 = (const float*)d_in[5];
    const float* b2 = (const float*)d_in[6];
    float* out = (float*)d_out;

    const int* row = ei;
    const int* col = ei + N_EDGES;

    float* ws = (float*)d_ws;
    float2* ein = (float2*)ws;                          // 25.6MB
    u64* packed_sh = (u64*)ws;                          // alias: dead before ein written
    float* xw = ws + 2 * (size_t)N_EDGES;               // N*32
    float* h  = xw + (size_t)N_NODES * HID;             // N*32
    float* hw = xw;                                     // alias: xw dead after gather1
    float* dinv = h + (size_t)N_NODES * HID;            // N
    int* cnt_total = (int*)(dinv + N_NODES);            // N
    int* offs = cnt_total + N_NODES;                    // N+1
    int* bsum = offs + N_NODES + 1;                     // 128
    int* shard_pref = bsum + 128;                       // 8N (3.2MB)
    unsigned short* pos = (unsigned short*)(shard_pref + (size_t)NSH * N_NODES);  // E (6.4MB)

    const int B = 256;

    k_zero<<<(NSH * N_NODES + B - 1) / B, B, 0, stream>>>(packed_sh);
    k_cnt<<<(N_EDGES + B - 1) / B, B, 0, stream>>>(col, w, packed_sh, pos);
    k_reduce<<<(N_NODES + B - 1) / B, B, 0, stream>>>(packed_sh, dinv, cnt_total, shard_pref);

    k_scanA<<<SCAN_NBLK, SCAN_TPB, 0, stream>>>(cnt_total, offs, bsum);
    k_scanB<<<1, 128, 0, stream>>>(bsum);
    k_scanC<<<SCAN_NBLK, SCAN_TPB, 0, stream>>>(offs, bsum);

    k_fill<<<(N_EDGES + B - 1) / B, B, 0, stream>>>(row, col, w, dinv, offs, shard_pref, pos, ein);

    k_gemm1<<<(N_NODES + 127) / 128, 128, 0, stream>>>(x, W1, xw);
    k_gather1<<<(N_NODES * HID) / B, B, 0, stream>>>(xw, dinv, ein, offs, b1, h);

    k_gemm2<<<(N_NODES + 63) / 64, B, 0, stream>>>(h, W2, hw);
    k_gather2<<<(N_NODES * NCLASS) / B, B, 0, stream>>>(hw, dinv, ein, offs, b2, out);
}